// Round 1
// baseline (48.587 us; speedup 1.0000x reference)
//
#include <hip/hip_runtime.h>

#define NBINS 100
#define NATOM 1024
#define PI_F 3.14159265358979323846f

__global__ void zero_ws(float* ws) {
    int t = blockIdx.x * blockDim.x + threadIdx.x;
    if (t < NBINS) ws[t] = 0.0f;
}

// grid = 256 blocks x 256 threads; each block handles 4 rows i, threads stride over j.
__global__ __launch_bounds__(256) void rdf_hist(const float* __restrict__ xyz,
                                                const float* __restrict__ cell,
                                                float* __restrict__ hist) {
    const float cx = cell[0], cy = cell[1], cz = cell[2];
    const float hx = 0.5f * cx, hy = 0.5f * cy, hz = 0.5f * cz;
    // width = 5/99; coeff = -0.5/width^2 = -0.5*(99/5)^2
    const float coeff = -0.5f * (99.0f * 99.0f) / (5.0f * 5.0f);
    const float cutsq = 5.5f * 5.5f;
    const float DB = 5.0f / 99.0f;   // offset spacing

    float acc[NBINS];
#pragma unroll
    for (int b = 0; b < NBINS; ++b) acc[b] = 0.0f;

    const int ROWS = 4;
    const int i0 = blockIdx.x * ROWS;

    for (int r = 0; r < ROWS; ++r) {
        const int i = i0 + r;
        const float xi = xyz[3 * i + 0];
        const float yi = xyz[3 * i + 1];
        const float zi = xyz[3 * i + 2];
        for (int j = threadIdx.x; j < NATOM; j += 256) {
            float dx = xyz[3 * j + 0] - xi;   // xyz[j] - xyz[i], matches reference
            float dy = xyz[3 * j + 1] - yi;
            float dz = xyz[3 * j + 2] - zi;
            // minimum-image PBC, exact replication of reference shift rule
            dx += (dx < -hx ? cx : 0.0f) - (dx >= hx ? cx : 0.0f);
            dy += (dy < -hy ? cy : 0.0f) - (dy >= hy ? cy : 0.0f);
            dz += (dz < -hz ? cz : 0.0f) - (dz >= hz ? cz : 0.0f);
            const float dsq = dx * dx + dy * dy + dz * dz;
            const bool m = (dsq < cutsq) && (dsq != 0.0f);
            // masked-out pairs: d huge -> exp underflows to exactly 0 for every bin
            const float d = m ? sqrtf(dsq) : 3.0e4f;
#pragma unroll
            for (int b = 0; b < NBINS; ++b) {
                const float t = d - DB * (float)b;
                acc[b] += __expf(coeff * t * t);
            }
        }
    }

    // wave (64-lane) butterfly reduce each bin
#pragma unroll
    for (int b = 0; b < NBINS; ++b) {
        float v = acc[b];
        v += __shfl_xor(v, 1, 64);
        v += __shfl_xor(v, 2, 64);
        v += __shfl_xor(v, 4, 64);
        v += __shfl_xor(v, 8, 64);
        v += __shfl_xor(v, 16, 64);
        v += __shfl_xor(v, 32, 64);
        acc[b] = v;   // all lanes now hold the wave sum
    }

    __shared__ float part[4][NBINS];
    const int wave = threadIdx.x >> 6;
    const int lane = threadIdx.x & 63;
    // distribute the 100 LDS stores across lanes (static indices only)
#pragma unroll
    for (int b = 0; b < NBINS; ++b) {
        if ((b & 63) == lane) part[wave][b] = acc[b];
    }
    __syncthreads();
    if (threadIdx.x < NBINS) {
        const float s = part[0][threadIdx.x] + part[1][threadIdx.x] +
                        part[2][threadIdx.x] + part[3][threadIdx.x];
        atomicAdd(&hist[threadIdx.x], s);
    }
}

// single block, 128 threads: normalize + bins + rdf epilogue
__global__ __launch_bounds__(128) void rdf_finalize(const float* __restrict__ hist,
                                                    float* __restrict__ out) {
    const int t = threadIdx.x;
    const float v = (t < NBINS) ? hist[t] : 0.0f;

    float s = v;
    s += __shfl_xor(s, 1, 64);
    s += __shfl_xor(s, 2, 64);
    s += __shfl_xor(s, 4, 64);
    s += __shfl_xor(s, 8, 64);
    s += __shfl_xor(s, 16, 64);
    s += __shfl_xor(s, 32, 64);

    __shared__ float wsum[2];
    if ((t & 63) == 0) wsum[t >> 6] = s;
    __syncthreads();
    const float total = wsum[0] + wsum[1];

    if (t < NBINS) {
        const float count = v / total;
        out[t] = count;                                   // output 0: count[100]
        const float b0 = 0.05f * (float)t;
        const float b1 = 0.05f * (float)(t + 1);
        const float vol = (4.0f * PI_F / 3.0f) * (b1 * b1 * b1 - b0 * b0 * b0);
        const float V = (4.0f / 3.0f) * PI_F * 125.0f;    // end^3 = 5^3
        out[2 * NBINS + 1 + t] = count * V / vol;         // output 2: rdf[100]
    }
    if (t < NBINS + 1) {
        out[NBINS + t] = 0.05f * (float)t;                // output 1: bins[101]
    }
}

extern "C" void kernel_launch(void* const* d_in, const int* in_sizes, int n_in,
                              void* d_out, int out_size, void* d_ws, size_t ws_size,
                              hipStream_t stream) {
    const float* xyz  = (const float*)d_in[0];
    const float* cell = (const float*)d_in[1];
    float* out  = (float*)d_out;
    float* hist = (float*)d_ws;

    zero_ws<<<1, 128, 0, stream>>>(hist);
    rdf_hist<<<256, 256, 0, stream>>>(xyz, cell, hist);
    rdf_finalize<<<1, 128, 0, stream>>>(hist, out);
}

// Round 2
// 31.455 us; speedup vs baseline: 1.5447x; 1.5447x over previous
//
#include <hip/hip_runtime.h>

#define NBINS 100
#define NATOM 1024
#define PI_F 3.14159265358979323846f

__global__ void zero_ws(float* ws) {
    if (threadIdx.x < NBINS) ws[threadIdx.x] = 0.0f;
}

// grid = 256 blocks x 1024 threads; block handles rows i0..i0+3, thread owns column j.
// Windowed Gaussian smear: coeff = -196.02, exp(coeff*t^2) < 1.5e-14 for |t| >= 8*DB,
// so a 16-bin window around floor(d/DB) captures everything to ~1e-7 absolute.
__global__ __launch_bounds__(1024) void rdf_hist(const float* __restrict__ xyz,
                                                 const float* __restrict__ cell,
                                                 float* __restrict__ hist) {
    const float cx = cell[0], cy = cell[1], cz = cell[2];
    const float hx = 0.5f * cx, hy = 0.5f * cy, hz = 0.5f * cz;
    const float coeff  = -0.5f * (99.0f * 99.0f) / (5.0f * 5.0f);  // -0.5/width^2
    const float cutsq  = 5.5f * 5.5f;
    const float DB     = 5.0f / 99.0f;    // bin-center spacing
    const float INV_DB = 99.0f / 5.0f;

    __shared__ float sh[NBINS];
    if (threadIdx.x < NBINS) sh[threadIdx.x] = 0.0f;
    __syncthreads();

    // each thread owns atom j; loads its position once (coalesced)
    const int j = threadIdx.x;
    const float xj = xyz[3 * j + 0];
    const float yj = xyz[3 * j + 1];
    const float zj = xyz[3 * j + 2];

    const int i0 = blockIdx.x * 4;
#pragma unroll
    for (int r = 0; r < 4; ++r) {
        const int i = i0 + r;               // block-uniform -> scalar loads
        const float xi = xyz[3 * i + 0];
        const float yi = xyz[3 * i + 1];
        const float zi = xyz[3 * i + 2];
        // dvec[i][j] = xyz[j] - xyz[i]; all ordered pairs covered exactly once
        float dx = xj - xi;
        float dy = yj - yi;
        float dz = zj - zi;
        // minimum-image PBC, exact replication of reference shift rule
        dx += (dx < -hx ? cx : 0.0f) - (dx >= hx ? cx : 0.0f);
        dy += (dy < -hy ? cy : 0.0f) - (dy >= hy ? cy : 0.0f);
        dz += (dz < -hz ? cz : 0.0f) - (dz >= hz ? cz : 0.0f);
        const float dsq = dx * dx + dy * dy + dz * dz;
        if (dsq != 0.0f && dsq < cutsq) {
            const float d    = sqrtf(dsq);
            const int   base = (int)(d * INV_DB) - 7;   // window [base, base+15]
            const float t0   = d - (float)base * DB;
#pragma unroll
            for (int k = 0; k < 16; ++k) {
                const float t = t0 - (float)k * DB;     // k*DB folds to a constant
                const float g = __expf(coeff * t * t);
                const int  bi = base + k;
                if ((unsigned)bi < NBINS) atomicAdd(&sh[bi], g);
            }
        }
    }

    __syncthreads();
    if (threadIdx.x < NBINS) atomicAdd(&hist[threadIdx.x], sh[threadIdx.x]);
}

// single block, 128 threads: normalize + bins + rdf epilogue
__global__ __launch_bounds__(128) void rdf_finalize(const float* __restrict__ hist,
                                                    float* __restrict__ out) {
    const int t = threadIdx.x;
    const float v = (t < NBINS) ? hist[t] : 0.0f;

    float s = v;
    s += __shfl_xor(s, 1, 64);
    s += __shfl_xor(s, 2, 64);
    s += __shfl_xor(s, 4, 64);
    s += __shfl_xor(s, 8, 64);
    s += __shfl_xor(s, 16, 64);
    s += __shfl_xor(s, 32, 64);

    __shared__ float wsum[2];
    if ((t & 63) == 0) wsum[t >> 6] = s;
    __syncthreads();
    const float total = wsum[0] + wsum[1];

    if (t < NBINS) {
        const float count = v / total;
        out[t] = count;                                   // output 0: count[100]
        const float b0 = 0.05f * (float)t;
        const float b1 = 0.05f * (float)(t + 1);
        const float vol = (4.0f * PI_F / 3.0f) * (b1 * b1 * b1 - b0 * b0 * b0);
        const float V = (4.0f / 3.0f) * PI_F * 125.0f;    // end^3 = 5^3
        out[2 * NBINS + 1 + t] = count * V / vol;         // output 2: rdf[100]
    }
    if (t < NBINS + 1) {
        out[NBINS + t] = 0.05f * (float)t;                // output 1: bins[101]
    }
}

extern "C" void kernel_launch(void* const* d_in, const int* in_sizes, int n_in,
                              void* d_out, int out_size, void* d_ws, size_t ws_size,
                              hipStream_t stream) {
    const float* xyz  = (const float*)d_in[0];
    const float* cell = (const float*)d_in[1];
    float* out  = (float*)d_out;
    float* hist = (float*)d_ws;

    zero_ws<<<1, 128, 0, stream>>>(hist);
    rdf_hist<<<256, 1024, 0, stream>>>(xyz, cell, hist);
    rdf_finalize<<<1, 128, 0, stream>>>(hist, out);
}